// Round 1
// baseline (192.327 us; speedup 1.0000x reference)
//
#include <hip/hip_runtime.h>
#include <hip/hip_bf16.h>
#include <cstdint>
#include <cstddef>

#define B_ 8
#define C_ 64
#define CI 32
#define N_ 4096

typedef __attribute__((ext_vector_type(8))) short bf16x8;
typedef __attribute__((ext_vector_type(4))) float f32x4;

__device__ __forceinline__ ushort f2bf(float x) {
  union { float f; uint32_t u; } v; v.f = x;
  uint32_t r = v.u + 0x7FFFu + ((v.u >> 16) & 1u);
  return (ushort)(r >> 16);
}

// -------- Kernel 1: three 1x1-conv projections, fp32 -> bf16 workspace ------
// theta_t: (B, N, CI) bf16, scaled by log2(e)  (so attention can use exp2)
// phi_t:   (B, N, CI) bf16
// gmat:    (B, CI, N) bf16
__global__ __launch_bounds__(256) void proj_kernel(
    const float* __restrict__ x,
    const float* __restrict__ Wg, const float* __restrict__ bg,
    const float* __restrict__ Wt, const float* __restrict__ bt,
    const float* __restrict__ Wp, const float* __restrict__ bp,
    ushort* __restrict__ theta_t, ushort* __restrict__ phi_t,
    ushort* __restrict__ gmat)
{
  const int b = blockIdx.y;
  const int n = blockIdx.x * 256 + threadIdx.x;
  const float* xb = x + ((size_t)b * C_) * N_ + n;

  float at[CI], ap[CI], ag[CI];
  #pragma unroll
  for (int d = 0; d < CI; ++d) { at[d] = bt[d]; ap[d] = bp[d]; ag[d] = bg[d]; }

  #pragma unroll 4
  for (int c = 0; c < C_; ++c) {
    const float xv = xb[(size_t)c * N_];
    #pragma unroll
    for (int d = 0; d < CI; ++d) {
      at[d] = fmaf(Wt[d * C_ + c], xv, at[d]);
      ap[d] = fmaf(Wp[d * C_ + c], xv, ap[d]);
      ag[d] = fmaf(Wg[d * C_ + c], xv, ag[d]);
    }
  }

  const float LOG2E = 1.44269504088896340736f;
  uint32_t wt[CI / 2], wp[CI / 2];
  #pragma unroll
  for (int k = 0; k < CI / 2; ++k) {
    wt[k] = (uint32_t)f2bf(at[2 * k] * LOG2E) |
            ((uint32_t)f2bf(at[2 * k + 1] * LOG2E) << 16);
    wp[k] = (uint32_t)f2bf(ap[2 * k]) | ((uint32_t)f2bf(ap[2 * k + 1]) << 16);
  }
  uint4* tdst = (uint4*)(theta_t + ((size_t)(b * N_) + n) * CI);
  uint4* pdst = (uint4*)(phi_t + ((size_t)(b * N_) + n) * CI);
  #pragma unroll
  for (int k = 0; k < CI / 8; ++k) {
    tdst[k] = make_uint4(wt[4 * k], wt[4 * k + 1], wt[4 * k + 2], wt[4 * k + 3]);
    pdst[k] = make_uint4(wp[4 * k], wp[4 * k + 1], wp[4 * k + 2], wp[4 * k + 3]);
  }
  #pragma unroll
  for (int d = 0; d < CI; ++d)
    gmat[((size_t)(b * CI) + d) * N_ + n] = f2bf(ag[d]);
}

// -------- Kernel 2: flash attention, swapped-operand MFMA ------------------
// yT: (B, CI, N) fp32 output (y transposed)
__global__ __launch_bounds__(256) void attn_kernel(
    const ushort* __restrict__ theta_t,
    const ushort* __restrict__ phi_t,
    const ushort* __restrict__ gmat,
    float* __restrict__ yT)
{
  __shared__ ushort Kt[64 * 32];      // K tile (m=64 rows, d=32), swizzled
  __shared__ ushort Vt[32 * 64];      // V tile (d=32 rows, m=64), swizzled
  __shared__ ushort Pt[4][16 * 64];   // per-wave P tile (n=16 rows, m=64), swizzled

  const int tid = threadIdx.x;
  const int lane = tid & 63;
  const int wave = tid >> 6;
  const int b = blockIdx.y;
  const int n0 = blockIdx.x * 64;
  const int nw = n0 + wave * 16;
  const int g4 = lane >> 4;    // 0..3
  const int c16 = lane & 15;   // 0..15: this lane's q-row within the wave tile

  // Q as MFMA B-operand: B[k=d][col=n]; lane holds theta_t[nw+c16][g4*8 + j]
  const bf16x8 qfrag =
      *(const bf16x8*)(theta_t + ((size_t)(b * N_ + nw + c16)) * CI + g4 * 8);

  f32x4 acc0 = {0.f, 0.f, 0.f, 0.f};   // yT[d=g4*4+r][n=c16]
  f32x4 acc1 = {0.f, 0.f, 0.f, 0.f};   // yT[d=16+g4*4+r][n=c16]
  float m_run = -INFINITY;
  float l_run = 0.f;

  // staging decomposition (256 threads, 16B each per tile)
  const int km = tid >> 2, kpart = tid & 3;   // Kt: row m, 16B part
  const int vd = tid >> 3, vp = tid & 7;      // Vt: row d, 16B part
  const ushort* ksrc = phi_t + ((size_t)(b * N_ + km)) * CI + kpart * 8;
  const ushort* vsrc = gmat + ((size_t)(b * CI + vd)) * N_ + vp * 8;
  char* kdst = (char*)Kt + ((km * 64 + kpart * 16) ^ ((km & 7) << 4));
  char* vdst = (char*)Vt + ((vd * 128 + vp * 16) ^ ((vd & 7) << 4));

  for (int m0 = 0; m0 < N_; m0 += 64) {
    __syncthreads();  // prior iteration's LDS reads done
    *(uint4*)kdst = *(const uint4*)(ksrc + (size_t)m0 * CI);
    *(uint4*)vdst = *(const uint4*)(vsrc + m0);
    __syncthreads();

    // f^T tile: mfma(A=K (m x d), B=Q (d x n)) -> D[m][n], lane: n=c16 fixed,
    // m = mt*16 + g4*4 + r  (lane-local row softmax!)
    f32x4 f[4];
    #pragma unroll
    for (int mt = 0; mt < 4; ++mt) {
      const int mrow = mt * 16 + c16;  // A-frag i-index = lane&15
      const bf16x8 kf = *(const bf16x8*)((const char*)Kt +
                          ((mrow * 64 + g4 * 16) ^ ((mrow & 7) << 4)));
      f[mt] = __builtin_amdgcn_mfma_f32_16x16x32_bf16(
          kf, qfrag, (f32x4){0.f, 0.f, 0.f, 0.f}, 0, 0, 0);
    }

    // online softmax, logits already in log2 units (theta pre-scaled)
    float pm = f[0][0];
    #pragma unroll
    for (int mt = 0; mt < 4; ++mt)
      #pragma unroll
      for (int r = 0; r < 4; ++r) pm = fmaxf(pm, f[mt][r]);
    pm = fmaxf(pm, __shfl_xor(pm, 16));
    pm = fmaxf(pm, __shfl_xor(pm, 32));

    const float mnew = fmaxf(m_run, pm);
    const float sc = __builtin_amdgcn_exp2f(m_run - mnew);
    m_run = mnew;

    float p[4][4];
    float psum = 0.f;
    #pragma unroll
    for (int mt = 0; mt < 4; ++mt)
      #pragma unroll
      for (int r = 0; r < 4; ++r) {
        p[mt][r] = __builtin_amdgcn_exp2f(f[mt][r] - mnew);
        psum += p[mt][r];
      }
    psum += __shfl_xor(psum, 16);
    psum += __shfl_xor(psum, 32);
    l_run = l_run * sc + psum;
    acc0 *= sc;
    acc1 *= sc;

    // P -> per-wave LDS tile [n=16][m=64] bf16, swizzled; 4 consecutive m
    // per (mt): pack to one b64 write
    #pragma unroll
    for (int mt = 0; mt < 4; ++mt) {
      uint2 w;
      w.x = (uint32_t)f2bf(p[mt][0]) | ((uint32_t)f2bf(p[mt][1]) << 16);
      w.y = (uint32_t)f2bf(p[mt][2]) | ((uint32_t)f2bf(p[mt][3]) << 16);
      *(uint2*)((char*)Pt[wave] +
                ((c16 * 128 + mt * 32 + g4 * 8) ^ ((c16 & 7) << 4))) = w;
    }
    asm volatile("s_waitcnt lgkmcnt(0)" ::: "memory");

    // PV swapped: mfma(A=V (d x m), B=P (m x n)) -> yT[d][n]
    #pragma unroll
    for (int ks = 0; ks < 2; ++ks) {
      const bf16x8 pfrag = *(const bf16x8*)((const char*)Pt[wave] +
                             ((c16 * 128 + ks * 64 + g4 * 16) ^ ((c16 & 7) << 4)));
      const int d0 = c16;
      const bf16x8 vf0 = *(const bf16x8*)((const char*)Vt +
                           ((d0 * 128 + ks * 64 + g4 * 16) ^ ((d0 & 7) << 4)));
      acc0 = __builtin_amdgcn_mfma_f32_16x16x32_bf16(vf0, pfrag, acc0, 0, 0, 0);
      const int d1 = 16 + c16;
      const bf16x8 vf1 = *(const bf16x8*)((const char*)Vt +
                           ((d1 * 128 + ks * 64 + g4 * 16) ^ ((d1 & 7) << 4)));
      acc1 = __builtin_amdgcn_mfma_f32_16x16x32_bf16(vf1, pfrag, acc1, 0, 0, 0);
    }
  }

  const float inv = 1.0f / l_run;  // lane-local (its own q-row)
  #pragma unroll
  for (int r = 0; r < 4; ++r) {
    yT[((size_t)(b * CI + g4 * 4 + r)) * N_ + nw + c16] = acc0[r] * inv;
    yT[((size_t)(b * CI + 16 + g4 * 4 + r)) * N_ + nw + c16] = acc1[r] * inv;
  }
}

// -------- Kernel 3: out = Ww @ y + bw + x ----------------------------------
__global__ __launch_bounds__(256) void outproj_kernel(
    const float* __restrict__ yT, const float* __restrict__ Ww,
    const float* __restrict__ bw, const float* __restrict__ x,
    float* __restrict__ out)
{
  const int b = blockIdx.y;
  const int n = blockIdx.x * 256 + threadIdx.x;
  float acc[C_];
  #pragma unroll
  for (int c = 0; c < C_; ++c) acc[c] = bw[c];
  #pragma unroll 4
  for (int d = 0; d < CI; ++d) {
    const float yv = yT[((size_t)(b * CI + d)) * N_ + n];
    #pragma unroll
    for (int c = 0; c < C_; ++c)
      acc[c] = fmaf(Ww[c * CI + d], yv, acc[c]);
  }
  #pragma unroll 4
  for (int c = 0; c < C_; ++c) {
    const size_t idx = ((size_t)(b * C_ + c)) * N_ + n;
    out[idx] = acc[c] + x[idx];
  }
}

extern "C" void kernel_launch(void* const* d_in, const int* in_sizes, int n_in,
                              void* d_out, int out_size, void* d_ws, size_t ws_size,
                              hipStream_t stream) {
  const float* x  = (const float*)d_in[0];
  const float* Wg = (const float*)d_in[1];
  const float* bg = (const float*)d_in[2];
  const float* Wt = (const float*)d_in[3];
  const float* bt = (const float*)d_in[4];
  const float* Wp = (const float*)d_in[5];
  const float* bp = (const float*)d_in[6];
  const float* Ww = (const float*)d_in[7];
  const float* bw = (const float*)d_in[8];
  float* out = (float*)d_out;

  char* ws = (char*)d_ws;
  ushort* theta_t = (ushort*)(ws);
  ushort* phi_t   = (ushort*)(ws + (size_t)2 * 1024 * 1024);
  ushort* gmat    = (ushort*)(ws + (size_t)4 * 1024 * 1024);
  float*  yT      = (float*)(ws + (size_t)6 * 1024 * 1024);

  proj_kernel<<<dim3(N_ / 256, B_), 256, 0, stream>>>(
      x, Wg, bg, Wt, bt, Wp, bp, theta_t, phi_t, gmat);
  attn_kernel<<<dim3(N_ / 64, B_), 256, 0, stream>>>(
      theta_t, phi_t, gmat, yT);
  outproj_kernel<<<dim3(N_ / 256, B_), 256, 0, stream>>>(
      yT, Ww, bw, x, out);
}

// Round 2
// 74.305 us; speedup vs baseline: 2.5884x; 2.5884x over previous
//
#include <hip/hip_runtime.h>
#include <hip/hip_bf16.h>
#include <cstdint>
#include <cstddef>

#define B_ 8
#define C_ 64
#define CI 32
#define N_ 4096

typedef __attribute__((ext_vector_type(8))) short bf16x8;
typedef __attribute__((ext_vector_type(4))) float f32x4;

__device__ __forceinline__ ushort f2bf(float x) {
  union { float f; uint32_t u; } v; v.f = x;
  uint32_t r = v.u + 0x7FFFu + ((v.u >> 16) & 1u);
  return (ushort)(r >> 16);
}

__device__ __forceinline__ uint32_t cvt_pk_bf16(float lo, float hi) {
  uint32_t r;
  asm("v_cvt_pk_bf16_f32 %0, %1, %2" : "=v"(r) : "v"(lo), "v"(hi));
  return r;
}

// -------- Kernel 1: 1x1-conv projections; blockIdx.z picks which one -------
// z=0: theta_t (B,N,CI) bf16 scaled by log2(e); z=1: phi_t (B,N,CI);
// z=2: gmat (B,CI,N)
__global__ __launch_bounds__(256) void proj_kernel(
    const float* __restrict__ x,
    const float* __restrict__ Wg, const float* __restrict__ bg,
    const float* __restrict__ Wt, const float* __restrict__ bt,
    const float* __restrict__ Wp, const float* __restrict__ bp,
    ushort* __restrict__ theta_t, ushort* __restrict__ phi_t,
    ushort* __restrict__ gmat)
{
  const int z = blockIdx.z;
  const float* W; const float* bias;
  if (z == 0)      { W = Wt; bias = bt; }
  else if (z == 1) { W = Wp; bias = bp; }
  else             { W = Wg; bias = bg; }

  const int b = blockIdx.y;
  const int n = blockIdx.x * 256 + threadIdx.x;
  const float* xb = x + ((size_t)b * C_) * N_ + n;

  float acc[CI];
  #pragma unroll
  for (int d = 0; d < CI; ++d) acc[d] = bias[d];

  #pragma unroll
  for (int cc = 0; cc < C_; cc += 8) {
    float xv[8];
    #pragma unroll
    for (int j = 0; j < 8; ++j) xv[j] = xb[(size_t)(cc + j) * N_];
    #pragma unroll
    for (int j = 0; j < 8; ++j)
      #pragma unroll
      for (int d = 0; d < CI; ++d)
        acc[d] = fmaf(W[d * C_ + cc + j], xv[j], acc[d]);
  }

  if (z == 2) {
    #pragma unroll
    for (int d = 0; d < CI; ++d)
      gmat[((size_t)(b * CI) + d) * N_ + n] = f2bf(acc[d]);
  } else {
    const float scale = (z == 0) ? 1.44269504088896340736f : 1.0f;
    uint32_t w[CI / 2];
    #pragma unroll
    for (int k = 0; k < CI / 2; ++k)
      w[k] = (uint32_t)f2bf(acc[2 * k] * scale) |
             ((uint32_t)f2bf(acc[2 * k + 1] * scale) << 16);
    ushort* base = (z == 0) ? theta_t : phi_t;
    uint4* dst = (uint4*)(base + ((size_t)(b * N_) + n) * CI);
    #pragma unroll
    for (int k = 0; k < CI / 8; ++k)
      dst[k] = make_uint4(w[4 * k], w[4 * k + 1], w[4 * k + 2], w[4 * k + 3]);
  }
}

// -------- Kernel 2: flash attention, split-m (2 halves), 8 waves/block -----
__global__ __launch_bounds__(512, 4) void attn_kernel(
    const ushort* __restrict__ theta_t,
    const ushort* __restrict__ phi_t,
    const ushort* __restrict__ gmat,
    float* __restrict__ yT)
{
  __shared__ ushort Kt[2][64 * 32];     // per-half K tile, swizzled
  __shared__ ushort Vt[2][32 * 64];     // per-half V tile, swizzled
  __shared__ ushort Pt[8][16 * 64];     // per-wave P tile, swizzled
  __shared__ float scratch[4][64][12];  // split-m merge: qg, lane, {m,l,acc0,acc1}

  const int tid = threadIdx.x;
  const int lane = tid & 63;
  const int wave = tid >> 6;
  const int qg = wave & 3;        // which 16-q group
  const int mh = wave >> 2;       // which m-half (0: [0,2048), 1: [2048,4096))
  const int bid = blockIdx.x;
  const int b = bid & 7;          // batch == XCD slot -> K/V L2-resident per XCD
  const int n0 = (bid >> 3) * 64;
  const int nw = n0 + qg * 16;
  const int g4 = lane >> 4;
  const int c16 = lane & 15;
  const int sw = (c16 & 7) << 4;

  const bf16x8 qfrag =
      *(const bf16x8*)(theta_t + ((size_t)(b * N_ + nw + c16)) * CI + g4 * 8);

  bf16x8 onesA;  // A-row 0 = 1.0 -> acc2 row 0 accumulates sum_m P[q][m]
  {
    const short ov = (c16 == 0) ? (short)0x3F80 : (short)0;
    #pragma unroll
    for (int j = 0; j < 8; ++j) onesA[j] = ov;
  }

  f32x4 acc0 = {0.f, 0.f, 0.f, 0.f};
  f32x4 acc1 = {0.f, 0.f, 0.f, 0.f};
  f32x4 acc2 = {0.f, 0.f, 0.f, 0.f};
  float m_run = -INFINITY;

  // loop-invariant LDS pointers
  const char* kf_base = (const char*)Kt[mh] + ((c16 * 64 + g4 * 16) ^ sw);
  char* pw[4];
  #pragma unroll
  for (int mt = 0; mt < 4; ++mt)
    pw[mt] = (char*)Pt[wave] + ((c16 * 128 + mt * 32 + g4 * 8) ^ sw);
  const char* pr[2]; const char* vr[2];
  #pragma unroll
  for (int ks = 0; ks < 2; ++ks) {
    pr[ks] = (const char*)Pt[wave] + ((c16 * 128 + ks * 64 + g4 * 16) ^ sw);
    vr[ks] = (const char*)Vt[mh] + ((c16 * 128 + ks * 64 + g4 * 16) ^ sw);
  }

  // staging: 512 threads, 1 K-chunk + 1 V-chunk (16B) each per iter
  const int khalf = tid >> 8;
  const int krem = tid & 255;
  const int km = krem >> 2, kpart = krem & 3;
  const int vd = krem >> 3, vp8 = krem & 7;
  const ushort* kp = phi_t + ((size_t)(b * N_ + khalf * 2048 + km)) * CI + kpart * 8;
  const ushort* vsp = gmat + ((size_t)(b * CI + vd)) * N_ + khalf * 2048 + vp8 * 8;
  char* kdst = (char*)Kt[khalf] + ((km * 64 + kpart * 16) ^ ((km & 7) << 4));
  char* vdst = (char*)Vt[khalf] + ((vd * 128 + vp8 * 16) ^ ((vd & 7) << 4));

  uint4 kreg = *(const uint4*)kp;  kp += 64 * CI;
  uint4 vreg = *(const uint4*)vsp; vsp += 64;
  *(uint4*)kdst = kreg;
  *(uint4*)vdst = vreg;
  __syncthreads();

  const int NT = 2048 / 64;
  for (int t = 0; t < NT; ++t) {
    const bool more = (t + 1 < NT);
    if (more) {  // T14: issue next tile's loads before compute
      kreg = *(const uint4*)kp;  kp += 64 * CI;
      vreg = *(const uint4*)vsp; vsp += 64;
    }

    f32x4 f[4];
    __builtin_amdgcn_s_setprio(1);
    #pragma unroll
    for (int mt = 0; mt < 4; ++mt) {
      const bf16x8 kf = *(const bf16x8*)(kf_base + mt * 1024);
      f[mt] = __builtin_amdgcn_mfma_f32_16x16x32_bf16(
          kf, qfrag, (f32x4){0.f, 0.f, 0.f, 0.f}, 0, 0, 0);
    }
    __builtin_amdgcn_s_setprio(0);

    float pm = fmaxf(
        fmaxf(fmaxf(fmaxf(f[0][0], f[0][1]), fmaxf(f[0][2], f[0][3])),
              fmaxf(fmaxf(f[1][0], f[1][1]), fmaxf(f[1][2], f[1][3]))),
        fmaxf(fmaxf(fmaxf(f[2][0], f[2][1]), fmaxf(f[2][2], f[2][3])),
              fmaxf(fmaxf(f[3][0], f[3][1]), fmaxf(f[3][2], f[3][3]))));
    pm = fmaxf(pm, __shfl_xor(pm, 16));
    pm = fmaxf(pm, __shfl_xor(pm, 32));

    if (__any(pm > m_run + 8.f)) {  // T13 defer-rescale (log2 units)
      const float mnew = fmaxf(m_run, pm);
      const float sc = __builtin_amdgcn_exp2f(m_run - mnew);
      m_run = mnew;
      acc0 *= sc; acc1 *= sc; acc2 *= sc;
    }

    #pragma unroll
    for (int mt = 0; mt < 4; ++mt) {
      const float p0 = __builtin_amdgcn_exp2f(f[mt][0] - m_run);
      const float p1 = __builtin_amdgcn_exp2f(f[mt][1] - m_run);
      const float p2 = __builtin_amdgcn_exp2f(f[mt][2] - m_run);
      const float p3 = __builtin_amdgcn_exp2f(f[mt][3] - m_run);
      uint2 wv;
      wv.x = cvt_pk_bf16(p0, p1);
      wv.y = cvt_pk_bf16(p2, p3);
      *(uint2*)pw[mt] = wv;
    }
    asm volatile("s_waitcnt lgkmcnt(0)" ::: "memory");

    __builtin_amdgcn_s_setprio(1);
    #pragma unroll
    for (int ks = 0; ks < 2; ++ks) {
      const bf16x8 pfrag = *(const bf16x8*)pr[ks];
      const bf16x8 vf0 = *(const bf16x8*)vr[ks];
      const bf16x8 vf1 = *(const bf16x8*)(vr[ks] + 2048);
      acc0 = __builtin_amdgcn_mfma_f32_16x16x32_bf16(vf0, pfrag, acc0, 0, 0, 0);
      acc1 = __builtin_amdgcn_mfma_f32_16x16x32_bf16(vf1, pfrag, acc1, 0, 0, 0);
      acc2 = __builtin_amdgcn_mfma_f32_16x16x32_bf16(onesA, pfrag, acc2, 0, 0, 0);
    }
    __builtin_amdgcn_s_setprio(0);

    __syncthreads();
    if (more) { *(uint4*)kdst = kreg; *(uint4*)vdst = vreg; }
    __syncthreads();
  }

  // l for this lane's q-row lives in lane c16 (g4==0), reg 0
  const float l_own = __shfl(acc2[0], c16, 64);

  if (mh == 1) {
    float* s = scratch[qg][lane];
    s[0] = m_run; s[1] = l_own;
    #pragma unroll
    for (int r = 0; r < 4; ++r) { s[2 + r] = acc0[r]; s[6 + r] = acc1[r]; }
  }
  __syncthreads();
  if (mh == 0) {
    const float* s = scratch[qg][lane];
    const float mb = s[0], lb = s[1];
    const float mM = fmaxf(m_run, mb);
    const float ea = __builtin_amdgcn_exp2f(m_run - mM);
    const float eb = __builtin_amdgcn_exp2f(mb - mM);
    const float inv = 1.0f / (l_own * ea + lb * eb);
    const float fa = ea * inv, fb = eb * inv;
    #pragma unroll
    for (int r = 0; r < 4; ++r) {
      yT[((size_t)(b * CI + g4 * 4 + r)) * N_ + nw + c16] =
          acc0[r] * fa + s[2 + r] * fb;
      yT[((size_t)(b * CI + 16 + g4 * 4 + r)) * N_ + nw + c16] =
          acc1[r] * fa + s[6 + r] * fb;
    }
  }
}

// -------- Kernel 3: out = Ww @ y + bw + x; blockIdx.z = channel quarter ----
__global__ __launch_bounds__(256) void outproj_kernel(
    const float* __restrict__ yT, const float* __restrict__ Ww,
    const float* __restrict__ bw, const float* __restrict__ x,
    float* __restrict__ out)
{
  const int b = blockIdx.y;
  const int c0 = blockIdx.z * 16;
  const int n = blockIdx.x * 256 + threadIdx.x;
  float acc[16];
  #pragma unroll
  for (int i = 0; i < 16; ++i) acc[i] = bw[c0 + i];
  #pragma unroll
  for (int dd = 0; dd < CI; dd += 8) {
    float yv[8];
    #pragma unroll
    for (int j = 0; j < 8; ++j)
      yv[j] = yT[((size_t)(b * CI + dd + j)) * N_ + n];
    #pragma unroll
    for (int j = 0; j < 8; ++j)
      #pragma unroll
      for (int i = 0; i < 16; ++i)
        acc[i] = fmaf(Ww[(c0 + i) * CI + dd + j], yv[j], acc[i]);
  }
  #pragma unroll
  for (int i = 0; i < 16; ++i) {
    const size_t idx = ((size_t)(b * C_ + c0 + i)) * N_ + n;
    out[idx] = acc[i] + x[idx];
  }
}

extern "C" void kernel_launch(void* const* d_in, const int* in_sizes, int n_in,
                              void* d_out, int out_size, void* d_ws, size_t ws_size,
                              hipStream_t stream) {
  const float* x  = (const float*)d_in[0];
  const float* Wg = (const float*)d_in[1];
  const float* bg = (const float*)d_in[2];
  const float* Wt = (const float*)d_in[3];
  const float* bt = (const float*)d_in[4];
  const float* Wp = (const float*)d_in[5];
  const float* bp = (const float*)d_in[6];
  const float* Ww = (const float*)d_in[7];
  const float* bw = (const float*)d_in[8];
  float* out = (float*)d_out;

  char* ws = (char*)d_ws;
  ushort* theta_t = (ushort*)(ws);
  ushort* phi_t   = (ushort*)(ws + (size_t)2 * 1024 * 1024);
  ushort* gmat    = (ushort*)(ws + (size_t)4 * 1024 * 1024);
  float*  yT      = (float*)(ws + (size_t)6 * 1024 * 1024);

  proj_kernel<<<dim3(N_ / 256, B_, 3), 256, 0, stream>>>(
      x, Wg, bg, Wt, bt, Wp, bp, theta_t, phi_t, gmat);
  attn_kernel<<<dim3(N_ / 64 * B_), 512, 0, stream>>>(
      theta_t, phi_t, gmat, yT);
  outproj_kernel<<<dim3(N_ / 256, B_, 4), 256, 0, stream>>>(
      yT, Ww, bw, x, out);
}

// Round 4
// 74.001 us; speedup vs baseline: 2.5990x; 1.0041x over previous
//
#include <hip/hip_runtime.h>
#include <hip/hip_bf16.h>
#include <cstdint>
#include <cstddef>

#define B_ 8
#define C_ 64
#define CI 32
#define N_ 4096
#define LOG2E 1.44269504088896340736f

typedef __attribute__((ext_vector_type(8))) short bf16x8;
typedef __attribute__((ext_vector_type(4))) float f32x4;

static __device__ __forceinline__ ushort f2bf(float x) {
  union { float f; uint32_t u; } v; v.f = x;
  uint32_t r = v.u + 0x7FFFu + ((v.u >> 16) & 1u);
  return (ushort)(r >> 16);
}

static __device__ __forceinline__ uint32_t cvt_pk_bf16(float lo, float hi) {
  uint32_t r;
  asm("v_cvt_pk_bf16_f32 %0, %1, %2" : "=v"(r) : "v"(lo), "v"(hi));
  return r;
}

// -------- Kernel 1: three 1x1-conv projections, fp32 -> bf16 workspace ------
// z=0: theta_t (B,N,CI) scaled by log2e; z=1: phi_t (B,N,CI); z=2: gmat (B,CI,N)
__global__ __launch_bounds__(256) void proj_kernel(
    const float* __restrict__ x,
    const float* __restrict__ Wg, const float* __restrict__ bg,
    const float* __restrict__ Wt, const float* __restrict__ bt,
    const float* __restrict__ Wp, const float* __restrict__ bp,
    ushort* __restrict__ theta_t, ushort* __restrict__ phi_t,
    ushort* __restrict__ gmat)
{
  const int z = blockIdx.z;
  const float* W; const float* bias;
  if (z == 0)      { W = Wt; bias = bt; }
  else if (z == 1) { W = Wp; bias = bp; }
  else             { W = Wg; bias = bg; }

  const int b = blockIdx.y;
  const int t = threadIdx.x;
  const int n = blockIdx.x * 64 + (t & 63);
  const int dq = t >> 6;                    // wave-uniform channel quarter
  const float* xb = x + ((size_t)b * C_) * N_ + n;
  const float* Wr = W + dq * 8 * C_;

  float acc[8];
  #pragma unroll
  for (int i = 0; i < 8; ++i) acc[i] = bias[dq * 8 + i];

  #pragma unroll 8
  for (int c = 0; c < C_; ++c) {
    const float xv = xb[(size_t)c * N_];
    #pragma unroll
    for (int i = 0; i < 8; ++i)
      acc[i] = fmaf(Wr[i * C_ + c], xv, acc[i]);
  }

  if (z == 2) {
    #pragma unroll
    for (int i = 0; i < 8; ++i)
      gmat[((size_t)(b * CI) + dq * 8 + i) * N_ + n] = f2bf(acc[i]);
  } else {
    const float scale = (z == 0) ? LOG2E : 1.0f;
    uint32_t w[4];
    #pragma unroll
    for (int k = 0; k < 4; ++k)
      w[k] = (uint32_t)f2bf(acc[2 * k] * scale) |
             ((uint32_t)f2bf(acc[2 * k + 1] * scale) << 16);
    ushort* base = (z == 0) ? theta_t : phi_t;
    *(uint4*)(base + ((size_t)(b * N_) + n) * CI + dq * 8) =
        make_uint4(w[0], w[1], w[2], w[3]);
  }
}

// -------- Kernel 2: flash attention; 4 waves = 4 m-quarters, q=64/wave -----
// P goes through a per-wave private LDS tile (ping-pong) and PV uses the
// verified 16x16x32 MFMA. No barriers in the main loop.
__global__ __launch_bounds__(256, 2) void attn_kernel(
    const ushort* __restrict__ theta_t,
    const ushort* __restrict__ phi_t,
    const ushort* __restrict__ gmat,
    const float* __restrict__ Ww, const float* __restrict__ bw,
    const float* __restrict__ x, float* __restrict__ out)
{
  __shared__ float scratch[2][64][40];   // merge slots; scratch[0] aliased as y
  __shared__ ushort Pt[4][2][16 * 64];   // per-wave ping-pong P tiles, swizzled
  __shared__ float WwL[C_ * CI];

  const int tid = threadIdx.x;
  const int lane = tid & 63;
  const int mh = tid >> 6;        // wave = m-quarter 0..3
  const int bid = blockIdx.x;
  const int b = bid & 7;          // batch -> XCD slot (K/V L2-resident)
  const int n0 = (bid >> 3) * 64;
  const int g4 = lane >> 4;
  const int c16 = lane & 15;
  const int sw = (c16 & 7) << 4;

  #pragma unroll
  for (int i = 0; i < 8; ++i) WwL[tid + i * 256] = Ww[tid + i * 256];

  // four q sub-tiles per wave (share every K/V fragment)
  bf16x8 qfrag[4];
  #pragma unroll
  for (int s = 0; s < 4; ++s)
    qfrag[s] = *(const bf16x8*)(theta_t +
        ((size_t)(b * N_ + n0 + s * 16 + c16)) * CI + g4 * 8);

  f32x4 acc[4][2];
  #pragma unroll
  for (int s = 0; s < 4; ++s)
    #pragma unroll
    for (int dk = 0; dk < 2; ++dk) acc[s][dk] = (f32x4){0.f, 0.f, 0.f, 0.f};
  float m_run[4] = {0.f, 0.f, 0.f, 0.f};
  float l_lane[4] = {0.f, 0.f, 0.f, 0.f};

  const int mq0 = mh * 1024;
  // K A-frag (16x16x32): row m = mq0 + t*64 + mt*16 + c16, d-slice g4*8
  const ushort* kbase = phi_t + ((size_t)(b * N_ + mq0 + c16)) * CI + g4 * 8;
  // V A-frag (16x16x32): row d = c16 (+16), m-slice t*64 + ks*32 + g4*8
  const ushort* vb0 = gmat + ((size_t)(b * CI + c16)) * N_ + mq0 + g4 * 8;
  const ushort* vb1 = vb0 + (size_t)16 * N_;

  // loop-invariant swizzled P-LDS pointers (write as D-layout, read as B-frag)
  char* pw[2][4]; const char* prd[2][2];
  #pragma unroll
  for (int pb = 0; pb < 2; ++pb) {
    #pragma unroll
    for (int mt = 0; mt < 4; ++mt)
      pw[pb][mt] = (char*)Pt[mh][pb] + ((c16 * 128 + mt * 32 + g4 * 8) ^ sw);
    #pragma unroll
    for (int ks = 0; ks < 2; ++ks)
      prd[pb][ks] = (const char*)Pt[mh][pb] + ((c16 * 128 + ks * 64 + g4 * 16) ^ sw);
  }

  bf16x8 kf[4];
  #pragma unroll
  for (int mt = 0; mt < 4; ++mt)
    kf[mt] = *(const bf16x8*)(kbase + (size_t)(mt * 16) * CI);

  const int NT = 16;
  for (int t = 0; t < NT; ++t) {
    bf16x8 vf0[2], vf1[2];
    #pragma unroll
    for (int ks = 0; ks < 2; ++ks) {
      vf0[ks] = *(const bf16x8*)(vb0 + t * 64 + ks * 32);
      vf1[ks] = *(const bf16x8*)(vb1 + t * 64 + ks * 32);
    }
    const int tn = (t + 1 < NT) ? t + 1 : t;   // next K tile prefetch
    bf16x8 kfn[4];
    #pragma unroll
    for (int mt = 0; mt < 4; ++mt)
      kfn[mt] = *(const bf16x8*)(kbase + (size_t)(tn * 64 + mt * 16) * CI);

    #pragma unroll
    for (int s = 0; s < 4; ++s) {
      const int pb = s & 1;
      f32x4 f[4];
      __builtin_amdgcn_s_setprio(1);
      #pragma unroll
      for (int mt = 0; mt < 4; ++mt)
        f[mt] = __builtin_amdgcn_mfma_f32_16x16x32_bf16(
            kf[mt], qfrag[s], (f32x4){0.f, 0.f, 0.f, 0.f}, 0, 0, 0);
      __builtin_amdgcn_s_setprio(0);

      // stale-max: p with current m_run; made exact by post-tile rescale
      float pm = -1e30f;
      float pv[4][4];
      #pragma unroll
      for (int mt = 0; mt < 4; ++mt) {
        #pragma unroll
        for (int r = 0; r < 4; ++r) {
          const float fv = f[mt][r];
          pm = fmaxf(pm, fv);
          pv[mt][r] = __builtin_amdgcn_exp2f(fv - m_run[s]);
        }
        l_lane[s] += (pv[mt][0] + pv[mt][1]) + (pv[mt][2] + pv[mt][3]);
      }
      #pragma unroll
      for (int mt = 0; mt < 4; ++mt) {
        uint2 wv;
        wv.x = cvt_pk_bf16(pv[mt][0], pv[mt][1]);
        wv.y = cvt_pk_bf16(pv[mt][2], pv[mt][3]);
        *(uint2*)pw[pb][mt] = wv;
      }
      asm volatile("s_waitcnt lgkmcnt(0)" ::: "memory");
      __builtin_amdgcn_sched_barrier(0);

      __builtin_amdgcn_s_setprio(1);
      #pragma unroll
      for (int ks = 0; ks < 2; ++ks) {
        const bf16x8 pfrag = *(const bf16x8*)prd[pb][ks];
        acc[s][0] = __builtin_amdgcn_mfma_f32_16x16x32_bf16(
            vf0[ks], pfrag, acc[s][0], 0, 0, 0);
        acc[s][1] = __builtin_amdgcn_mfma_f32_16x16x32_bf16(
            vf1[ks], pfrag, acc[s][1], 0, 0, 0);
      }
      __builtin_amdgcn_s_setprio(0);

      if (__any(pm > m_run[s] + 8.f)) {   // T13 defer-rescale (log2 units)
        float pmr = fmaxf(pm, __shfl_xor(pm, 16));
        pmr = fmaxf(pmr, __shfl_xor(pmr, 32));
        const float mnew = fmaxf(m_run[s], pmr);
        const float sc = __builtin_amdgcn_exp2f(m_run[s] - mnew);
        m_run[s] = mnew;
        acc[s][0] *= sc; acc[s][1] *= sc; l_lane[s] *= sc;
      }
    }
    #pragma unroll
    for (int mt = 0; mt < 4; ++mt) kf[mt] = kfn[mt];
  }

  // total l per q-column: sum the 4 g4 partials
  #pragma unroll
  for (int s = 0; s < 4; ++s) {
    l_lane[s] += __shfl_xor(l_lane[s], 16);
    l_lane[s] += __shfl_xor(l_lane[s], 32);
  }

  auto store_state = [&](float* sp) {
    #pragma unroll
    for (int s = 0; s < 4; ++s) {
      sp[s * 10 + 0] = m_run[s]; sp[s * 10 + 1] = l_lane[s];
      #pragma unroll
      for (int r = 0; r < 4; ++r) {
        sp[s * 10 + 2 + r] = acc[s][0][r];
        sp[s * 10 + 6 + r] = acc[s][1][r];
      }
    }
  };
  auto merge_state = [&](const float* sp) {
    #pragma unroll
    for (int s = 0; s < 4; ++s) {
      const float mb = sp[s * 10 + 0], lb = sp[s * 10 + 1];
      const float mM = fmaxf(m_run[s], mb);
      const float ea = __builtin_amdgcn_exp2f(m_run[s] - mM);
      const float eb = __builtin_amdgcn_exp2f(mb - mM);
      #pragma unroll
      for (int r = 0; r < 4; ++r) {
        acc[s][0][r] = acc[s][0][r] * ea + sp[s * 10 + 2 + r] * eb;
        acc[s][1][r] = acc[s][1][r] * ea + sp[s * 10 + 6 + r] * eb;
      }
      l_lane[s] = l_lane[s] * ea + lb * eb;
      m_run[s] = mM;
    }
  };

  if (mh == 1) store_state(scratch[0][lane]);
  if (mh == 3) store_state(scratch[1][lane]);
  __syncthreads();
  if (mh == 0) merge_state(scratch[0][lane]);
  if (mh == 2) merge_state(scratch[1][lane]);
  __syncthreads();
  if (mh == 2) store_state(scratch[0][lane]);
  __syncthreads();
  if (mh == 0) merge_state(scratch[0][lane]);
  __syncthreads();                  // all merge reads done before alias

  float* yl = &scratch[0][0][0];    // y[32][66] fp32 (padded), fits slot 0
  if (mh == 0) {
    #pragma unroll
    for (int s = 0; s < 4; ++s) {
      const float inv = 1.0f / l_lane[s];
      const int q = s * 16 + c16;
      #pragma unroll
      for (int r = 0; r < 4; ++r) {
        yl[(g4 * 4 + r) * 66 + q]      = acc[s][0][r] * inv;
        yl[(16 + g4 * 4 + r) * 66 + q] = acc[s][1][r] * inv;
      }
    }
  }
  __syncthreads();

  // ---- fused out-projection + residual: out = Ww @ y + bw + x ----
  const int nl = tid & 63;
  const int cg = tid >> 6;          // wave-uniform channel group of 16
  float oacc[16];
  #pragma unroll
  for (int i = 0; i < 16; ++i) oacc[i] = bw[cg * 16 + i];
  #pragma unroll
  for (int d = 0; d < CI; ++d) {
    const float yv = yl[d * 66 + nl];
    #pragma unroll
    for (int i = 0; i < 16; ++i)
      oacc[i] = fmaf(WwL[(cg * 16 + i) * CI + d], yv, oacc[i]);
  }
  #pragma unroll
  for (int i = 0; i < 16; ++i) {
    const size_t idx = ((size_t)(b * C_ + cg * 16 + i)) * N_ + n0 + nl;
    out[idx] = oacc[i] + x[idx];
  }
}

extern "C" void kernel_launch(void* const* d_in, const int* in_sizes, int n_in,
                              void* d_out, int out_size, void* d_ws, size_t ws_size,
                              hipStream_t stream) {
  const float* x  = (const float*)d_in[0];
  const float* Wg = (const float*)d_in[1];
  const float* bg = (const float*)d_in[2];
  const float* Wt = (const float*)d_in[3];
  const float* bt = (const float*)d_in[4];
  const float* Wp = (const float*)d_in[5];
  const float* bp = (const float*)d_in[6];
  const float* Ww = (const float*)d_in[7];
  const float* bw = (const float*)d_in[8];
  float* out = (float*)d_out;

  char* ws = (char*)d_ws;
  ushort* theta_t = (ushort*)(ws);
  ushort* phi_t   = (ushort*)(ws + (size_t)2 * 1024 * 1024);
  ushort* gmat    = (ushort*)(ws + (size_t)4 * 1024 * 1024);

  proj_kernel<<<dim3(N_ / 64, B_, 3), 256, 0, stream>>>(
      x, Wg, bg, Wt, bt, Wp, bp, theta_t, phi_t, gmat);
  attn_kernel<<<dim3((N_ / 64) * B_), 256, 0, stream>>>(
      theta_t, phi_t, gmat, Ww, bw, x, out);
}

// Round 7
// 73.221 us; speedup vs baseline: 2.6267x; 1.0107x over previous
//
#include <hip/hip_runtime.h>
#include <hip/hip_bf16.h>
#include <cstdint>
#include <cstddef>

#define B_ 8
#define C_ 64
#define CI 32
#define N_ 4096
#define LOG2E 1.44269504088896340736f

typedef __attribute__((ext_vector_type(8))) short bf16x8;
typedef __attribute__((ext_vector_type(4))) float f32x4;

static __device__ __forceinline__ ushort f2bf(float x) {
  union { float f; uint32_t u; } v; v.f = x;
  uint32_t r = v.u + 0x7FFFu + ((v.u >> 16) & 1u);
  return (ushort)(r >> 16);
}

static __device__ __forceinline__ uint32_t cvt_pk_bf16(float lo, float hi) {
  uint32_t r;
  asm("v_cvt_pk_bf16_f32 %0, %1, %2" : "=v"(r) : "v"(lo), "v"(hi));
  return r;
}

// -------- Kernel 1: 1x1-conv projections (r4-proven, z-split) --------------
// z=0: theta_t (B,N,CI) scaled by log2e; z=1: phi_t (B,N,CI); z=2: gmat (B,CI,N)
__global__ __launch_bounds__(256) void proj_kernel(
    const float* __restrict__ x,
    const float* __restrict__ Wg, const float* __restrict__ bg,
    const float* __restrict__ Wt, const float* __restrict__ bt,
    const float* __restrict__ Wp, const float* __restrict__ bp,
    ushort* __restrict__ theta_t, ushort* __restrict__ phi_t,
    ushort* __restrict__ gmat)
{
  const int z = blockIdx.z;
  const float* W; const float* bias;
  if (z == 0)      { W = Wt; bias = bt; }
  else if (z == 1) { W = Wp; bias = bp; }
  else             { W = Wg; bias = bg; }

  const int b = blockIdx.y;
  const int t = threadIdx.x;
  const int n = blockIdx.x * 64 + (t & 63);
  const int dq = t >> 6;                    // wave-uniform channel quarter
  const float* xb = x + ((size_t)b * C_) * N_ + n;
  const float* Wr = W + dq * 8 * C_;

  float acc[8];
  #pragma unroll
  for (int i = 0; i < 8; ++i) acc[i] = bias[dq * 8 + i];

  #pragma unroll 8
  for (int c = 0; c < C_; ++c) {
    const float xv = xb[(size_t)c * N_];
    #pragma unroll
    for (int i = 0; i < 8; ++i)
      acc[i] = fmaf(Wr[i * C_ + c], xv, acc[i]);
  }

  if (z == 2) {
    #pragma unroll
    for (int i = 0; i < 8; ++i)
      gmat[((size_t)(b * CI) + dq * 8 + i) * N_ + n] = f2bf(acc[i]);
  } else {
    const float scale = (z == 0) ? LOG2E : 1.0f;
    uint32_t w[4];
    #pragma unroll
    for (int k = 0; k < 4; ++k)
      w[k] = (uint32_t)f2bf(acc[2 * k] * scale) |
             ((uint32_t)f2bf(acc[2 * k + 1] * scale) << 16);
    ushort* base = (z == 0) ? theta_t : phi_t;
    *(uint4*)(base + ((size_t)(b * N_) + n) * CI + dq * 8) =
        make_uint4(w[0], w[1], w[2], w[3]);
  }
}

// -------- Kernel 2: flash attention -----------------------------------------
// 8 waves = 8 m-eighths, q=64/wave. Inner loop = r4's proven code (stale-max,
// defer-rescale, scalar l, ping-pong P, fence). Max-aware 3-round merge.
__global__ __launch_bounds__(512, 4) void attn_kernel(
    const ushort* __restrict__ theta_t,
    const ushort* __restrict__ phi_t,
    const ushort* __restrict__ gmat,
    const float* __restrict__ Ww, const float* __restrict__ bw,
    const float* __restrict__ x, float* __restrict__ out)
{
  // Pt (main loop) and accS (merge phase) time-share the same 32KB.
  __shared__ union {
    ushort pt[8][2][16 * 64];     // per-wave ping-pong P tiles
    float  accS[4][32][64];       // merge acc slots [slot][j][lane]
  } Sh;
  __shared__ float mlS[4][8][64]; // merge m/l slots  [slot][j][lane]
  __shared__ float WwL[C_ * CI];  // 8KB
  __shared__ float Yl[32 * 66];   // y tile (padded), 8.4KB

  const int tid = threadIdx.x;
  const int lane = tid & 63;
  const int mh = tid >> 6;        // wave = m-eighth 0..7
  const int bid = blockIdx.x;
  const int b = bid & 7;          // batch -> XCD slot (K/V L2-resident)
  const int n0 = (bid >> 3) * 64;
  const int g4 = lane >> 4;
  const int c16 = lane & 15;
  const int sw = (c16 & 7) << 4;

  #pragma unroll
  for (int i = 0; i < 4; ++i) WwL[tid + i * 512] = Ww[tid + i * 512];

  // four q sub-tiles per wave (share every K/V fragment)
  bf16x8 qfrag[4];
  #pragma unroll
  for (int s = 0; s < 4; ++s)
    qfrag[s] = *(const bf16x8*)(theta_t +
        ((size_t)(b * N_ + n0 + s * 16 + c16)) * CI + g4 * 8);

  f32x4 acc[4][2];
  #pragma unroll
  for (int s = 0; s < 4; ++s) {
    acc[s][0] = (f32x4){0.f, 0.f, 0.f, 0.f};
    acc[s][1] = (f32x4){0.f, 0.f, 0.f, 0.f};
  }
  float m_run[4] = {0.f, 0.f, 0.f, 0.f};
  float l_lane[4] = {0.f, 0.f, 0.f, 0.f};

  const int mq0 = mh * 512;
  // K A-frag (16x16x32): row m = mq0 + t*64 + mt*16 + c16, d-slice g4*8
  const ushort* kbase = phi_t + ((size_t)(b * N_ + mq0 + c16)) * CI + g4 * 8;
  // V A-frag: row d = c16 (+16), m-slice t*64 + ks*32 + g4*8
  const ushort* vb0 = gmat + ((size_t)(b * CI + c16)) * N_ + mq0 + g4 * 8;
  const ushort* vb1 = vb0 + (size_t)16 * N_;

  // loop-invariant swizzled P-LDS pointers (write D-layout, read B-frag)
  char* pw[2][4]; const char* prd[2][2];
  #pragma unroll
  for (int pb = 0; pb < 2; ++pb) {
    #pragma unroll
    for (int mt = 0; mt < 4; ++mt)
      pw[pb][mt] = (char*)Sh.pt[mh][pb] + ((c16 * 128 + mt * 32 + g4 * 8) ^ sw);
    #pragma unroll
    for (int ks = 0; ks < 2; ++ks)
      prd[pb][ks] = (const char*)Sh.pt[mh][pb] +
                    ((c16 * 128 + ks * 64 + g4 * 16) ^ sw);
  }

  const int NT = 8;               // 512 rows / 64 per tile
  for (int t = 0; t < NT; ++t) {
    bf16x8 kf[4];
    #pragma unroll
    for (int mt = 0; mt < 4; ++mt)
      kf[mt] = *(const bf16x8*)(kbase + (size_t)(t * 64 + mt * 16) * CI);
    bf16x8 vf0[2], vf1[2];
    #pragma unroll
    for (int ks = 0; ks < 2; ++ks) {
      vf0[ks] = *(const bf16x8*)(vb0 + t * 64 + ks * 32);
      vf1[ks] = *(const bf16x8*)(vb1 + t * 64 + ks * 32);
    }

    #pragma unroll
    for (int s = 0; s < 4; ++s) {
      const int pb = s & 1;
      f32x4 f[4];
      __builtin_amdgcn_s_setprio(1);
      #pragma unroll
      for (int mt = 0; mt < 4; ++mt)
        f[mt] = __builtin_amdgcn_mfma_f32_16x16x32_bf16(
            kf[mt], qfrag[s], (f32x4){0.f, 0.f, 0.f, 0.f}, 0, 0, 0);
      __builtin_amdgcn_s_setprio(0);

      // stale-max: p with current m_run; made exact by post-tile rescale
      float pm = -1e30f;
      float pv[4][4];
      #pragma unroll
      for (int mt = 0; mt < 4; ++mt) {
        #pragma unroll
        for (int rr = 0; rr < 4; ++rr) {
          const float fv = f[mt][rr];
          pm = fmaxf(pm, fv);
          pv[mt][rr] = __builtin_amdgcn_exp2f(fv - m_run[s]);
        }
        l_lane[s] += (pv[mt][0] + pv[mt][1]) + (pv[mt][2] + pv[mt][3]);
      }
      #pragma unroll
      for (int mt = 0; mt < 4; ++mt) {
        uint2 wv;
        wv.x = cvt_pk_bf16(pv[mt][0], pv[mt][1]);
        wv.y = cvt_pk_bf16(pv[mt][2], pv[mt][3]);
        *(uint2*)pw[pb][mt] = wv;
      }
      // compiler cannot relate pw/prd (XOR'd char*): pin write->read order
      asm volatile("s_waitcnt lgkmcnt(0)" ::: "memory");
      __builtin_amdgcn_sched_barrier(0);

      __builtin_amdgcn_s_setprio(1);
      #pragma unroll
      for (int ks = 0; ks < 2; ++ks) {
        const bf16x8 pfrag = *(const bf16x8*)prd[pb][ks];
        acc[s][0] = __builtin_amdgcn_mfma_f32_16x16x32_bf16(
            vf0[ks], pfrag, acc[s][0], 0, 0, 0);
        acc[s][1] = __builtin_amdgcn_mfma_f32_16x16x32_bf16(
            vf1[ks], pfrag, acc[s][1], 0, 0, 0);
      }
      __builtin_amdgcn_s_setprio(0);

      if (__any(pm > m_run[s] + 8.f)) {   // T13 defer-rescale (log2 units)
        float pmr = fmaxf(pm, __shfl_xor(pm, 16));
        pmr = fmaxf(pmr, __shfl_xor(pmr, 32));
        const float mnew = fmaxf(m_run[s], pmr);
        const float sc = __builtin_amdgcn_exp2f(m_run[s] - mnew);
        m_run[s] = mnew;
        acc[s][0] *= sc; acc[s][1] *= sc; l_lane[s] *= sc;
      }
    }
  }

  // total l per q-column: sum the 4 g4 partials (m_run already g4-uniform)
  #pragma unroll
  for (int s = 0; s < 4; ++s) {
    l_lane[s] += __shfl_xor(l_lane[s], 16);
    l_lane[s] += __shfl_xor(l_lane[s], 32);
  }

  // ---- split-m merge: max-aware flash combine, 3-round tree ----
  #pragma unroll
  for (int r = 4; r >= 1; r >>= 1) {
    __syncthreads();                       // prior reads done (incl. Pt use)
    if (mh >= r && mh < 2 * r) {
      float* ad = &Sh.accS[mh - r][0][0] + lane;
      float* md = &mlS[mh - r][0][0] + lane;
      #pragma unroll
      for (int s = 0; s < 4; ++s) {
        #pragma unroll
        for (int rr = 0; rr < 4; ++rr) {
          ad[(s * 8 + rr) * 64]     = acc[s][0][rr];
          ad[(s * 8 + 4 + rr) * 64] = acc[s][1][rr];
        }
        md[s * 64]       = m_run[s];
        md[(4 + s) * 64] = l_lane[s];
      }
    }
    __syncthreads();
    if (mh < r) {
      const float* as_ = &Sh.accS[mh][0][0] + lane;
      const float* ms_ = &mlS[mh][0][0] + lane;
      #pragma unroll
      for (int s = 0; s < 4; ++s) {
        const float mb = ms_[s * 64];
        const float lb = ms_[(4 + s) * 64];
        const float mM = fmaxf(m_run[s], mb);
        const float ea = __builtin_amdgcn_exp2f(m_run[s] - mM);
        const float eb = __builtin_amdgcn_exp2f(mb - mM);
        #pragma unroll
        for (int rr = 0; rr < 4; ++rr) {
          acc[s][0][rr] = acc[s][0][rr] * ea + as_[(s * 8 + rr) * 64] * eb;
          acc[s][1][rr] = acc[s][1][rr] * ea + as_[(s * 8 + 4 + rr) * 64] * eb;
        }
        l_lane[s] = l_lane[s] * ea + lb * eb;
        m_run[s] = mM;
      }
    }
  }
  __syncthreads();                         // all merge reads done

  if (mh == 0) {
    #pragma unroll
    for (int s = 0; s < 4; ++s) {
      const float inv = 1.0f / l_lane[s];
      const int q = s * 16 + c16;
      #pragma unroll
      for (int rr = 0; rr < 4; ++rr) {
        Yl[(g4 * 4 + rr) * 66 + q]      = acc[s][0][rr] * inv;
        Yl[(16 + g4 * 4 + rr) * 66 + q] = acc[s][1][rr] * inv;
      }
    }
  }
  __syncthreads();

  // ---- fused out-projection + residual: out = Ww @ y + bw + x ----
  const int nl = tid & 63;
  const int cg = tid >> 6;          // wave-uniform channel group of 8
  float oacc[8];
  #pragma unroll
  for (int i = 0; i < 8; ++i) oacc[i] = bw[cg * 8 + i];
  #pragma unroll
  for (int d = 0; d < CI; ++d) {
    const float yv = Yl[d * 66 + nl];
    #pragma unroll
    for (int i = 0; i < 8; ++i)
      oacc[i] = fmaf(WwL[(cg * 8 + i) * CI + d], yv, oacc[i]);
  }
  #pragma unroll
  for (int i = 0; i < 8; ++i) {
    const size_t idx = ((size_t)(b * C_ + cg * 8 + i)) * N_ + n0 + nl;
    out[idx] = oacc[i] + x[idx];
  }
}

extern "C" void kernel_launch(void* const* d_in, const int* in_sizes, int n_in,
                              void* d_out, int out_size, void* d_ws, size_t ws_size,
                              hipStream_t stream) {
  const float* x  = (const float*)d_in[0];
  const float* Wg = (const float*)d_in[1];
  const float* bg = (const float*)d_in[2];
  const float* Wt = (const float*)d_in[3];
  const float* bt = (const float*)d_in[4];
  const float* Wp = (const float*)d_in[5];
  const float* bp = (const float*)d_in[6];
  const float* Ww = (const float*)d_in[7];
  const float* bw = (const float*)d_in[8];
  float* out = (float*)d_out;

  char* ws = (char*)d_ws;
  ushort* theta_t = (ushort*)(ws);
  ushort* phi_t   = (ushort*)(ws + (size_t)2 * 1024 * 1024);
  ushort* gmat    = (ushort*)(ws + (size_t)4 * 1024 * 1024);

  proj_kernel<<<dim3(N_ / 64, B_, 3), 256, 0, stream>>>(
      x, Wg, bg, Wt, bt, Wp, bp, theta_t, phi_t, gmat);
  attn_kernel<<<dim3((N_ / 64) * B_), 512, 0, stream>>>(
      theta_t, phi_t, gmat, Ww, bw, x, out);
}